// Round 5
// baseline (619.327 us; speedup 1.0000x reference)
//
#include <hip/hip_runtime.h>
#include <hip/hip_bf16.h>
#include <stdint.h>

#define B_ 32
#define T_ 2048
#define H_ 1024
#define M_ (B_*T_)

typedef __bf16 bf16x8 __attribute__((ext_vector_type(8)));
typedef float  f32x4  __attribute__((ext_vector_type(4)));
typedef float  f32x16 __attribute__((ext_vector_type(16)));

__device__ __forceinline__ float tanh_fast(float x) {
    float e = __expf(2.0f * x);
    return 1.0f - 2.0f / (e + 1.0f);
}

__device__ __forceinline__ bf16x8 cvt2(f32x4 f0, f32x4 f1) {
    bf16x8 h;
    h[0] = (__bf16)f0[0]; h[1] = (__bf16)f0[1]; h[2] = (__bf16)f0[2]; h[3] = (__bf16)f0[3];
    h[4] = (__bf16)f1[0]; h[5] = (__bf16)f1[1]; h[6] = (__bf16)f1[2]; h[7] = (__bf16)f1[3];
    return h;
}

// async 16B global->LDS (HW dest = wave-uniform base + lane*16)
__device__ __forceinline__ void gl_lds16(const __bf16* g, __bf16* l) {
    __builtin_amdgcn_global_load_lds(
        (const __attribute__((address_space(1))) void*)g,
        (__attribute__((address_space(3))) void*)l, 16, 0, 0);
}

// ---------------- K0: fused prep (W_enc -> bf16 fragment tiles ; dec_p matvec) ----------------
__global__ __launch_bounds__(256) void k_prep(const float* __restrict__ We,
                                              __bf16* __restrict__ Wt,
                                              const float* __restrict__ dec,
                                              const float* __restrict__ Wd,
                                              float* __restrict__ decp) {
    __shared__ float dec8[8][1024];
    int bx = blockIdx.x;
    int tid = threadIdx.x;
    if (bx < 512) {
        int tg = bx * 256 + tid;             // 131072 cells
        int lane = tg & 63;
        int c = (tg >> 6) & 31;
        int s = tg >> 11;                    // 0..63
        int o = c * 32 + (lane & 31);
        int k = s * 16 + (lane >> 5) * 8;
        const f32x4* src = (const f32x4*)&We[(size_t)o * H_ + k];
        *(bf16x8*)&Wt[(size_t)tg * 8] = cvt2(src[0], src[1]);
    } else {
        int bx2 = bx - 512;                  // 0..63
        int oc = bx2 >> 2, bg = bx2 & 3;
        int b0 = bg * 8;
        {   // stage 8 dec rows into LDS
            int r = tid >> 5, c4 = (tid & 31) * 4;
            const float* drp = &dec[(size_t)(b0 + r) * H_];
#pragma unroll
            for (int j = 0; j < 8; ++j)
                *(f32x4*)&dec8[r][c4 + j * 128] = *(const f32x4*)&drp[c4 + j * 128];
        }
        __syncthreads();
        int ol = tid & 63, bi = tid >> 6;    // wave-uniform bi -> LDS broadcast reads
        int o = oc * 64 + ol;
        const f32x4* wr = (const f32x4*)&Wd[(size_t)o * H_];
        const f32x4* d0 = (const f32x4*)&dec8[bi][0];
        const f32x4* d1 = (const f32x4*)&dec8[bi + 4][0];
        f32x4 a0 = {0.f,0.f,0.f,0.f}, a1 = {0.f,0.f,0.f,0.f};
#pragma unroll 8
        for (int i = 0; i < 256; ++i) {
            f32x4 wv = wr[i];
            a0 += wv * d0[i];
            a1 += wv * d1[i];
        }
        decp[(b0 + bi) * H_ + o]     = a0[0] + a0[1] + a0[2] + a0[3];
        decp[(b0 + bi + 4) * H_ + o] = a1[0] + a1[1] + a1[2] + a1[3];
    }
}

// ---------------- K0b: enc f32 -> bf16 pre-tiled for k_scores DMA staging ----------------
// enc_t[rg2][ck][cell 0..1023] where cell = (s2*4+rt)*64 + q2*32 + rW holds bf16x8 of
// enc[rg2*128 + rt*32 + rW][ck*64 + s2*16 + q2*8 ..+8]. 2048 blocks = 512 rg2 x 4 rt.
// Reads: 256B contiguous per 8 rows; writes: 128B contiguous segments. Pure stream.
__global__ __launch_bounds__(256) void k_prep_enc(const float* __restrict__ enc,
                                                  __bf16* __restrict__ enc_t) {
    int bx = blockIdx.x;
    int rg2 = bx >> 2, rt = bx & 3;
    int tid = threadIdx.x;
    int w = tid >> 6, lane = tid & 63;
    int r3 = lane >> 3, o3 = lane & 7;
    int rW = w * 8 + r3;                                  // row within the 32-row rt slab
    int row = rg2 * 128 + rt * 32 + rW;
    const float* src = &enc[(size_t)row * H_ + o3 * 8];
    __bf16* dst = enc_t + (size_t)rg2 * 131072
                + (((o3 >> 1) * 4 + rt) * 64 + (o3 & 1) * 32 + rW) * 8;
#pragma unroll 4
    for (int j = 0; j < 16; ++j) {
        f32x4 a = *(const f32x4*)(src + j * 64);
        f32x4 b = *(const f32x4*)(src + j * 64 + 4);
        *(bf16x8*)&dst[(size_t)j * 8192] = cvt2(a, b);
    }
}

// ---------------- K1: fused GEMM + tanh + dot(v) -> score partials ----------------
// BM=128, BN=256: 2048 blocks = 512 row-groups (128 rows) x 4 col-groups, 4 waves.
// Wave = 128 rows x 64 cols (acc[4][2] = 128 regs). Rationale (R4 post-mortem): kernel is
// L2-traffic-bound; per-MFMA-cycle demand = A/BN + B/BM bytes. BM 64->128 halves B traffic
// (2GB->1GB); pre-tiled bf16 A (enc_t) halves A bytes and enables global_load_lds staging
// (0-conflict linear LDS, no cvt VALU, no staging regs). 2 x 16 KB double buffer, 2 blk/CU.
__global__ __launch_bounds__(256, 2) void k_scores(const __bf16* __restrict__ enc_t,
                                                   const float* __restrict__ decp,
                                                   const __bf16* __restrict__ Wt,
                                                   const float* __restrict__ v,
                                                   float* __restrict__ scores_p) {
    __shared__ __bf16 A_lds[2][8192];   // 2 x 16 KB: cell (s2*4+rt)*64+lane -> bf16x8
    __shared__ float red[4][128];

    const int tid = threadIdx.x;
    const int w = tid >> 6, lane = tid & 63;
    const int l5 = lane & 31, q2 = lane >> 5;

    // XCD-swizzled decode: 4 col-groups of one row-group share an XCD (L2 A/B reuse)
    const int bx = blockIdx.x;
    const int xs = bx & 7;
    const int q = bx >> 3;
    const int nt = q & 3;                   // col-group (256 cols)
    const int rg2 = (q >> 2) * 8 + xs;      // row-group 0..511 (128 rows each)
    const int m0 = rg2 * 128;
    const int b = m0 >> 11;
    const int cg0 = nt * 8 + w * 2;         // global 32-col tile index

    float dp[2], vvv[2];
#pragma unroll
    for (int ct = 0; ct < 2; ++ct) {
        int col = (cg0 + ct) * 32 + l5;
        dp[ct]  = decp[b * H_ + col];
        vvv[ct] = v[col];
    }

    f32x16 acc[4][2];
#pragma unroll
    for (int rt = 0; rt < 4; ++rt)
#pragma unroll
        for (int ct = 0; ct < 2; ++ct)
#pragma unroll
            for (int g = 0; g < 16; ++g)
                acc[rt][ct][g] = dp[ct];

    // staging source: thread's cell (i*256 + tid) of chunk ck
    const __bf16* gsrc = enc_t + (size_t)rg2 * 131072 + (size_t)tid * 8;

    // ---- prologue: stage chunk 0 into buf 0 ----
#pragma unroll
    for (int i = 0; i < 4; ++i)
        gl_lds16(gsrc + i * 2048, &A_lds[0][(i * 256 + tid) * 8]);

    // ---- B ring prologue: slices 0..1 ----
    bf16x8 bb[2][2];
#pragma unroll
    for (int p = 0; p < 2; ++p)
#pragma unroll
        for (int ct = 0; ct < 2; ++ct)
            bb[p][ct] = *(const bf16x8*)&Wt[(((size_t)p * 32 + cg0 + ct) * 64 + lane) * 8];

    __syncthreads();   // drains vmcnt(0): chunk 0 staged

    int cur = 0;
#pragma unroll 1
    for (int ck = 0; ck < 16; ++ck) {
        // issue async stage of chunk ck+1 into the other buffer; flies across the MFMAs
        if (ck < 15) {
            const __bf16* gs = gsrc + (size_t)(ck + 1) * 8192;
            __bf16* dst = A_lds[cur ^ 1];
#pragma unroll
            for (int i = 0; i < 4; ++i)
                gl_lds16(gs + i * 2048, &dst[(i * 256 + tid) * 8]);
        }

        const __bf16* buf = A_lds[cur];

#pragma unroll
        for (int sl = 0; sl < 4; ++sl) {
            const int s = ck * 4 + sl;
            // A fragments: 4 row-tiles, each a contiguous 1024B wave read (0-conflict)
            bf16x8 a0 = *(const bf16x8*)&buf[((sl * 4 + 0) * 64 + lane) * 8];
            bf16x8 a1 = *(const bf16x8*)&buf[((sl * 4 + 1) * 64 + lane) * 8];
            bf16x8 a2 = *(const bf16x8*)&buf[((sl * 4 + 2) * 64 + lane) * 8];
            bf16x8 a3 = *(const bf16x8*)&buf[((sl * 4 + 3) * 64 + lane) * 8];
            bf16x8 w0 = bb[s & 1][0], w1 = bb[s & 1][1];

            // prefetch B slice s+2 (L2-resident Wt) into the slot just freed
            {
                int sn = (s + 2) & 63;
#pragma unroll
                for (int ct = 0; ct < 2; ++ct)
                    bb[s & 1][ct] = *(const bf16x8*)&Wt[(((size_t)sn * 32 + cg0 + ct) * 64 + lane) * 8];
            }

            __builtin_amdgcn_s_setprio(1);
            acc[0][0] = __builtin_amdgcn_mfma_f32_32x32x16_bf16(a0, w0, acc[0][0], 0, 0, 0);
            acc[0][1] = __builtin_amdgcn_mfma_f32_32x32x16_bf16(a0, w1, acc[0][1], 0, 0, 0);
            acc[1][0] = __builtin_amdgcn_mfma_f32_32x32x16_bf16(a1, w0, acc[1][0], 0, 0, 0);
            acc[1][1] = __builtin_amdgcn_mfma_f32_32x32x16_bf16(a1, w1, acc[1][1], 0, 0, 0);
            acc[2][0] = __builtin_amdgcn_mfma_f32_32x32x16_bf16(a2, w0, acc[2][0], 0, 0, 0);
            acc[2][1] = __builtin_amdgcn_mfma_f32_32x32x16_bf16(a2, w1, acc[2][1], 0, 0, 0);
            acc[3][0] = __builtin_amdgcn_mfma_f32_32x32x16_bf16(a3, w0, acc[3][0], 0, 0, 0);
            acc[3][1] = __builtin_amdgcn_mfma_f32_32x32x16_bf16(a3, w1, acc[3][1], 0, 0, 0);
            __builtin_amdgcn_s_setprio(0);
        }

        __syncthreads();   // drains vmcnt(0): chunk ck+1 landed; all reads of buf done
        cur ^= 1;
    }

    // ---- epilogue ----
    float sp[4][16];
#pragma unroll
    for (int rt = 0; rt < 4; ++rt)
#pragma unroll
        for (int g = 0; g < 16; ++g)
            sp[rt][g] = tanh_fast(acc[rt][0][g]) * vvv[0] + tanh_fast(acc[rt][1][g]) * vvv[1];

#pragma unroll
    for (int rt = 0; rt < 4; ++rt)
#pragma unroll
        for (int g = 0; g < 16; ++g) {
            float s = sp[rt][g];
            s += __shfl_xor(s, 1);
            s += __shfl_xor(s, 2);
            s += __shfl_xor(s, 4);
            s += __shfl_xor(s, 8);
            s += __shfl_xor(s, 16);
            sp[rt][g] = s;
        }

    if (l5 == 0) {
#pragma unroll
        for (int rt = 0; rt < 4; ++rt)
#pragma unroll
            for (int g = 0; g < 16; ++g) {
                int row = rt * 32 + (g & 3) + 8 * (g >> 2) + 4 * q2;
                red[w][row] = sp[rt][g];
            }
    }
    __syncthreads();
    if (tid < 128) {
        float s = red[0][tid] + red[1][tid] + red[2][tid] + red[3][tid];
        scores_p[nt * M_ + m0 + tid] = s;   // per-col-group partial, no atomics
    }
}

// ---------------- K2: fused masked-softmax + context partial ----------------
__global__ __launch_bounds__(256) void k_ctx(const float* __restrict__ scores_p,
                                             const int* __restrict__ mask,
                                             const float* __restrict__ enc,
                                             float* __restrict__ attn,
                                             float* __restrict__ ctxp) {
    int bx = blockIdx.x;
    int b = bx >> 4, seg = bx & 15;
    int tid = threadIdx.x;
    int w = tid >> 6, lane = tid & 63;
    __shared__ float sm[2][4];
    __shared__ float wa[128];

    float val[8];
    float mx = -3e38f;
#pragma unroll
    for (int ii = 0; ii < 8; ++ii) {
        int idx = b * T_ + tid + ii * 256;
        float s = scores_p[idx] + scores_p[M_ + idx] + scores_p[2 * M_ + idx] + scores_p[3 * M_ + idx];
        s = (mask[idx] == 0) ? -1e9f : s;
        val[ii] = s;
        mx = fmaxf(mx, s);
    }
#pragma unroll
    for (int m = 1; m <= 32; m <<= 1) mx = fmaxf(mx, __shfl_xor(mx, m));
    if (lane == 0) sm[0][w] = mx;
    __syncthreads();
    mx = fmaxf(fmaxf(sm[0][0], sm[0][1]), fmaxf(sm[0][2], sm[0][3]));
    float lsum = 0.f;
#pragma unroll
    for (int ii = 0; ii < 8; ++ii) {
        val[ii] = __expf(val[ii] - mx);
        lsum += val[ii];
    }
#pragma unroll
    for (int m = 1; m <= 32; m <<= 1) lsum += __shfl_xor(lsum, m);
    if (lane == 0) sm[1][w] = lsum;
    __syncthreads();
    float inv = 1.0f / (sm[1][0] + sm[1][1] + sm[1][2] + sm[1][3]);

    if (seg == 0) {
#pragma unroll
        for (int ii = 0; ii < 8; ++ii)
            attn[b * T_ + tid + ii * 256] = val[ii] * inv;
    }
    {
        int half = seg & 1, ii0 = seg >> 1;
        if ((tid >> 7) == half) wa[tid & 127] = val[ii0] * inv;
    }
    __syncthreads();

    int t0 = seg * 128;
    const float* ep = &enc[((size_t)b * T_ + t0) * H_ + tid * 4];
    f32x4 acc = {0.f, 0.f, 0.f, 0.f};
#pragma unroll 8
    for (int t = 0; t < 128; ++t) {
        float a = wa[t];
        acc += a * *(const f32x4*)(ep + (size_t)t * H_);
    }
    *(f32x4*)&ctxp[((size_t)(seg * B_ + b)) * H_ + tid * 4] = acc;
}

// ---------------- K3: deterministic reduce of the 16 segment partials ----------------
__global__ __launch_bounds__(256) void k_red(const float* __restrict__ ctxp,
                                             float* __restrict__ ctx) {
    int i = blockIdx.x * 256 + threadIdx.x;
    float s = 0.f;
#pragma unroll
    for (int sg = 0; sg < 16; ++sg)
        s += ctxp[(size_t)sg * (B_ * H_) + i];
    ctx[i] = s;
}

extern "C" void kernel_launch(void* const* d_in, const int* in_sizes, int n_in,
                              void* d_out, int out_size, void* d_ws, size_t ws_size,
                              hipStream_t stream) {
    (void)in_sizes; (void)n_in; (void)out_size; (void)ws_size;
    const float* dec  = (const float*)d_in[0];
    const float* enc  = (const float*)d_in[1];
    const int*   mask = (const int*)d_in[2];
    const float* We   = (const float*)d_in[3];
    const float* Wd   = (const float*)d_in[4];
    const float* v    = (const float*)d_in[5];

    float* out = (float*)d_out;                 // [0,32768) context ; [32768,98304) attn
    char* ws = (char*)d_ws;
    float*  decp     = (float*)ws;                                   // 128 KB
    float*  scores_p = (float*)(ws + 131072);                        // 1 MB
    __bf16* Wt       = (__bf16*)(ws + 131072 + 1048576);             // 2 MB
    float*  ctxp     = (float*)(ws + 131072 + 1048576 + 2097152);    // 2 MB
    __bf16* enc_t    = (__bf16*)(ws + 131072 + 1048576 + 2097152 + 2097152); // 128 MB

    k_prep    <<<576, 256, 0, stream>>>(We, Wt, dec, Wd, decp);
    k_prep_enc<<<2048, 256, 0, stream>>>(enc, enc_t);
    k_scores  <<<2048, 256, 0, stream>>>(enc_t, decp, Wt, v, scores_p);
    k_ctx     <<<512, 256, 0, stream>>>(scores_p, mask, enc, out + B_ * H_, ctxp);
    k_red     <<<128, 256, 0, stream>>>(ctxp, out);
}